// Round 3
// baseline (1176.328 us; speedup 1.0000x reference)
//
#include <hip/hip_runtime.h>

#define N_ATOMS 21
#define DPAIR 210      // 21*20/2
#define X3 63          // 3*N_ATOMS
#define MT 16          // m-tile per block iteration
#define NCHUNK 8       // m-chunks (grid.x)

__device__ __forceinline__ int pair_idx(int a, int o) {
    int hi = a > o ? a : o;
    int lo = a > o ? o : a;
    return hi * (hi - 1) / 2 + lo;
}

// ---------------- kernel 1: per-batch pair geometry ----------------
__global__ void geom_kernel(const float* __restrict__ r,
                            float* __restrict__ xs_ws, float* __restrict__ xs3_ws,
                            float* __restrict__ xs5_ws, float* __restrict__ dkl_ws,
                            float* __restrict__ c3_ws) {
    int b = blockIdx.x;
    int tid = threadIdx.x;
    __shared__ float rs[X3];
    if (tid < X3) rs[tid] = r[b * X3 + tid];
    __syncthreads();
    if (tid < DPAIR) {
        int i = (int)((1.0f + sqrtf(1.0f + 8.0f * (float)tid)) * 0.5f);
        while (i * (i - 1) / 2 > tid) --i;
        while ((i + 1) * i / 2 <= tid) ++i;
        int j = tid - i * (i - 1) / 2;   // i > j
        float dx = rs[3 * i + 0] - rs[3 * j + 0];
        float dy = rs[3 * i + 1] - rs[3 * j + 1];
        float dz = rs[3 * i + 2] - rs[3 * j + 2];
        float n2 = dx * dx + dy * dy + dz * dz;
        float inv = 1.0f / sqrtf(n2);      // xs
        float inv2 = inv * inv;
        float x3 = inv2 * inv;
        float x5 = x3 * inv2;
        int gidx = b * DPAIR + tid;
        xs_ws[gidx] = inv;
        xs3_ws[gidx] = x3;
        xs5_ws[gidx] = x5;
        dkl_ws[gidx * 3 + 0] = dx;
        dkl_ws[gidx * 3 + 1] = dy;
        dkl_ws[gidx * 3 + 2] = dz;
        c3_ws[gidx * 3 + 0] = -x3 * dx;   // contrib = -xs^3 * dkl
        c3_ws[gidx * 3 + 1] = -x3 * dy;
        c3_ws[gidx * 3 + 2] = -x3 * dz;
    }
}

// ---------------- kernel 2: main m-loop ----------------
// grid = (NCHUNK, B), 256 threads.
// Accumulates (atomically):
//   outHess[b,x,y] += sum_m U[m,x]*XJ[m,y] - XJ[m,x]*V[m,y]
//   gx_ws[b,d]     += sum_m w1*A[m,d] + g*Xt[m,d]
//   e_ws[b]        += sum_m w1*XA ;  s2_ws[b] += sum_m g   (g = ef*XA)
__global__ __launch_bounds__(256) void main_kernel(
    const float* __restrict__ Xt, const float* __restrict__ A,
    const float* __restrict__ xs_ws, const float* __restrict__ c3_ws,
    float* __restrict__ outHess,
    float* __restrict__ gx_ws, float* __restrict__ e_ws, float* __restrict__ s2_ws,
    int Mtot)
{
    const float Q    = 0.22360679774997896f;   // sqrt(5)/SIG
    const float EFC  = 0.0008333333333333334f; // q^4/3
    const float INVQ2 = 20.0f;                 // 1/q^2

    int chunk = blockIdx.x;
    int b = blockIdx.y;
    int tid = threadIdx.x;

    __shared__ float Xt_tile[MT][DPAIR];
    __shared__ float A_tile[MT][DPAIR];
    __shared__ float XJ_lds[MT][64];
    __shared__ float U_lds[MT][64];
    __shared__ float V_lds[MT][64];
    __shared__ float xs_s[DPAIR];
    __shared__ float c3_s[DPAIR * 3];
    __shared__ float w1_s[MT], g_s[MT], c1_s[MT], ef_s[MT], xa_s[MT];

    if (tid < DPAIR) xs_s[tid] = xs_ws[b * DPAIR + tid];
    for (int idx = tid; idx < DPAIR * 3; idx += 256) c3_s[idx] = c3_ws[b * DPAIR * 3 + idx];

    int MCH = (Mtot + NCHUNK - 1) / NCHUNK;
    int m0 = chunk * MCH;
    int m1 = min(Mtot, m0 + MCH);

    float acc[4][4];
    #pragma unroll
    for (int i = 0; i < 4; ++i)
        #pragma unroll
        for (int j = 0; j < 4; ++j) acc[i][j] = 0.f;
    float gxp = 0.f, e_acc = 0.f, s2_acc = 0.f;

    int tx = tid >> 4, ty = tid & 15;
    int mtg = tid >> 4, lg = tid & 15;

    for (int t0 = m0; t0 < m1; t0 += MT) {
        // ---- stage Xt/A rows ----
        for (int idx = tid; idx < MT * DPAIR; idx += 256) {
            int mm = idx / DPAIR;
            int dd = idx - mm * DPAIR;
            int row = t0 + mm;
            row = row < Mtot ? row : Mtot - 1;
            Xt_tile[mm][dd] = Xt[row * DPAIR + dd];
            A_tile[mm][dd]  = A[row * DPAIR + dd];
        }
        __syncthreads();
        // ---- per-m scalars (16 lanes per m) ----
        {
            float s2 = 0.f, sxa = 0.f;
            for (int d = lg; d < DPAIR; d += 16) {
                float diff = xs_s[d] - Xt_tile[mtg][d];
                s2 = fmaf(diff, diff, s2);
                sxa = fmaf(diff, A_tile[mtg][d], sxa);
            }
            for (int o = 8; o >= 1; o >>= 1) {
                s2  += __shfl_xor(s2, o, 16);
                sxa += __shfl_xor(sxa, o, 16);
            }
            if (lg == 0) {
                bool valid = (t0 + mtg) < m1;
                float dist = sqrtf(s2);
                float ef = valid ? EFC * expf(-Q * dist) : 0.f;
                float w1 = ef * (1.f + Q * dist) * INVQ2;
                float g  = ef * sxa;
                float c1v = dist > 0.f ? Q * g / dist : 0.f;
                w1_s[mtg] = w1; g_s[mtg] = g; c1_s[mtg] = c1v; ef_s[mtg] = ef; xa_s[mtg] = sxa;
            }
        }
        __syncthreads();
        // ---- grad_x partial + energy/S2 partial ----
        if (tid < DPAIR) {
            #pragma unroll
            for (int mt = 0; mt < MT; ++mt)
                gxp += w1_s[mt] * A_tile[mt][tid] + g_s[mt] * Xt_tile[mt][tid];
        }
        if (tid == 0) {
            #pragma unroll
            for (int mt = 0; mt < MT; ++mt) { e_acc += w1_s[mt] * xa_s[mt]; s2_acc += g_s[mt]; }
        }
        // ---- build XJ / U / V (sparse jac application, gather per (atom,comp)) ----
        #pragma unroll
        for (int rr = 0; rr < 4; ++rr) {
            int mt = rr * 4 + (tid >> 6);
            int ac = tid & 63;
            if (ac < X3) {
                int a = ac / 3;
                int c = ac - 3 * a;
                float xjv = 0.f, ajv = 0.f;
                #pragma unroll
                for (int o = 0; o < N_ATOMS; ++o) {
                    if (o == a) continue;
                    int p = pair_idx(a, o);
                    float sgn = a > o ? 1.f : -1.f;
                    float c3v = sgn * c3_s[p * 3 + c];
                    xjv = fmaf(xs_s[p] - Xt_tile[mt][p], c3v, xjv);
                    ajv = fmaf(A_tile[mt][p], c3v, ajv);
                }
                XJ_lds[mt][ac] = xjv;
                U_lds[mt][ac]  = c1_s[mt] * xjv - ef_s[mt] * ajv;
                V_lds[mt][ac]  = ef_s[mt] * ajv;
            } else {
                XJ_lds[mt][63] = 0.f; U_lds[mt][63] = 0.f; V_lds[mt][63] = 0.f;
            }
        }
        __syncthreads();
        // ---- 63x63 outer-product accumulation (4x4 per thread over 64x64 padded) ----
        #pragma unroll
        for (int mt = 0; mt < MT; ++mt) {
            const float4* XJ4 = (const float4*)XJ_lds[mt];
            const float4* U4  = (const float4*)U_lds[mt];
            const float4* V4  = (const float4*)V_lds[mt];
            float4 u = U4[tx], xxv = XJ4[tx], yyv = XJ4[ty], vv = V4[ty];
            float uu[4]  = {u.x, u.y, u.z, u.w};
            float xxa[4] = {xxv.x, xxv.y, xxv.z, xxv.w};
            float yya[4] = {yyv.x, yyv.y, yyv.z, yyv.w};
            float vva[4] = {vv.x, vv.y, vv.z, vv.w};
            #pragma unroll
            for (int i = 0; i < 4; ++i)
                #pragma unroll
                for (int j = 0; j < 4; ++j)
                    acc[i][j] += uu[i] * yya[j] - xxa[i] * vva[j];
        }
        __syncthreads();
    }

    // ---- write partials ----
    #pragma unroll
    for (int i = 0; i < 4; ++i) {
        int x = 4 * tx + i;
        if (x >= X3) continue;
        #pragma unroll
        for (int j = 0; j < 4; ++j) {
            int y = 4 * ty + j;
            if (y >= X3) continue;
            atomicAdd(&outHess[((size_t)b * X3 + x) * X3 + y], acc[i][j]);
        }
    }
    if (tid < DPAIR) atomicAdd(&gx_ws[b * DPAIR + tid], gxp);
    if (tid == 0) { atomicAdd(&e_ws[b], e_acc); atomicAdd(&s2_ws[b], s2_acc); }
}

// ---------------- kernel 3: finalize (energy, grad, hessian corrections) ----------------
__global__ void finalize_kernel(
    const float* __restrict__ xs_ws, const float* __restrict__ xs3_ws,
    const float* __restrict__ xs5_ws, const float* __restrict__ dkl_ws,
    const float* __restrict__ c3_ws, const float* __restrict__ gx_ws,
    const float* __restrict__ e_ws, const float* __restrict__ s2_ws,
    float* __restrict__ out, int Bn)
{
    int b = blockIdx.x, tid = threadIdx.x;
    __shared__ float gx_s[DPAIR], xs3_s[DPAIR], xs5_s[DPAIR];
    __shared__ float c3s[DPAIR * 3], dkl_s[DPAIR * 3];
    float S2 = s2_ws[b];
    if (tid < DPAIR) {
        gx_s[tid]  = gx_ws[b * DPAIR + tid] - S2 * xs_ws[b * DPAIR + tid];
        xs3_s[tid] = xs3_ws[b * DPAIR + tid];
        xs5_s[tid] = xs5_ws[b * DPAIR + tid];
    }
    for (int idx = tid; idx < DPAIR * 3; idx += 256) {
        c3s[idx]   = c3_ws[b * DPAIR * 3 + idx];
        dkl_s[idx] = dkl_ws[b * DPAIR * 3 + idx];
    }
    __syncthreads();

    if (tid == 0) out[b] = e_ws[b];   // energy (STD=1, C=0)

    if (tid < X3) {  // grad[b, 3a+c] = sum over incident pairs of sign*gx[p]*c3[p][c]
        int a = tid / 3;
        int c = tid - 3 * a;
        float s = 0.f;
        #pragma unroll
        for (int o = 0; o < N_ATOMS; ++o) {
            if (o == a) continue;
            int p = pair_idx(a, o);
            float sgn = a > o ? 1.f : -1.f;
            s += sgn * gx_s[p] * c3s[p * 3 + c];
        }
        out[Bn + b * X3 + tid] = s;
    }

    float* hess = out + Bn + (size_t)Bn * X3 + (size_t)b * X3 * X3;
    for (int idx = tid; idx < X3 * X3; idx += 256) {
        int x = idx / X3, y = idx - X3 * x;
        int a1 = x / 3, ci = x - 3 * a1;
        int a2 = y / 3, cj = y - 3 * a2;
        float val = hess[idx];
        if (a1 != a2) {
            int p = pair_idx(a1, a2);
            float cc = c3s[p * 3 + ci] * c3s[p * 3 + cj];
            float ht = 3.f * gx_s[p] * xs5_s[p] * dkl_s[p * 3 + ci] * dkl_s[p * 3 + cj]
                       + (ci == cj ? -gx_s[p] * xs3_s[p] : 0.f);
            // JJ off-diag block = -c3 (x) c3  ->  -S2*JJ = +S2*cc ; assembly adds -h_t
            val += S2 * cc - ht;
        } else {
            int a = a1;
            #pragma unroll
            for (int o = 0; o < N_ATOMS; ++o) {
                if (o == a) continue;
                int p = pair_idx(a, o);
                float cc = c3s[p * 3 + ci] * c3s[p * 3 + cj];
                float ht = 3.f * gx_s[p] * xs5_s[p] * dkl_s[p * 3 + ci] * dkl_s[p * 3 + cj]
                           + (ci == cj ? -gx_s[p] * xs3_s[p] : 0.f);
                // JJ diag block = +c3 (x) c3 ; assembly adds +h_t
                val += -S2 * cc + ht;
            }
        }
        hess[idx] = val;
    }
}

extern "C" void kernel_launch(void* const* d_in, const int* in_sizes, int n_in,
                              void* d_out, int out_size, void* d_ws, size_t ws_size,
                              hipStream_t stream) {
    const float* r  = (const float*)d_in[0];
    const float* Xt = (const float*)d_in[1];
    const float* A  = (const float*)d_in[2];
    int Bn   = in_sizes[0] / X3;     // 64
    int Mtot = in_sizes[1] / DPAIR;  // 6000
    float* out = (float*)d_out;

    float* ws     = (float*)d_ws;
    float* gx_ws  = ws;                               // Bn*210 (atomic, zeroed)
    float* e_ws   = gx_ws + (size_t)Bn * DPAIR;       // Bn     (atomic, zeroed)
    float* s2_ws  = e_ws + Bn;                        // Bn     (atomic, zeroed)
    float* xs_ws  = s2_ws + Bn;                       // Bn*210
    float* xs3_ws = xs_ws + (size_t)Bn * DPAIR;       // Bn*210
    float* xs5_ws = xs3_ws + (size_t)Bn * DPAIR;      // Bn*210
    float* dkl_ws = xs5_ws + (size_t)Bn * DPAIR;      // Bn*630
    float* c3_ws  = dkl_ws + (size_t)Bn * DPAIR * 3;  // Bn*630

    hipMemsetAsync(d_out, 0, (size_t)out_size * sizeof(float), stream);
    hipMemsetAsync(ws, 0, ((size_t)Bn * DPAIR + 2 * (size_t)Bn) * sizeof(float), stream);

    geom_kernel<<<Bn, 256, 0, stream>>>(r, xs_ws, xs3_ws, xs5_ws, dkl_ws, c3_ws);

    dim3 grid(NCHUNK, Bn);
    main_kernel<<<grid, 256, 0, stream>>>(Xt, A, xs_ws, c3_ws,
        out + Bn + (size_t)Bn * X3, gx_ws, e_ws, s2_ws, Mtot);

    finalize_kernel<<<Bn, 256, 0, stream>>>(xs_ws, xs3_ws, xs5_ws, dkl_ws, c3_ws,
        gx_ws, e_ws, s2_ws, out, Bn);
}